// Round 12
// baseline (505.414 us; speedup 1.0000x reference)
//
#include <hip/hip_runtime.h>
#include <hip/hip_cooperative_groups.h>

namespace cg = cooperative_groups;

// GCN layer: out = Ahat @ x @ W^T + bias, Ahat = D^-1/2 (A + I) D^-1/2
// R12: single COOPERATIVE mega-kernel (391 blocks x 512t), grid.sync between
// phases replaces 3 dispatch boundaries + memset node:
//  P0 zero own gcnt + bin local (R7-proven 512t body)  -> grid.sync
//  P1 gof global atomics + ebuf copy-out
//  P2 gemm: stage+MFMA 2x128-row sub-tiles into REGISTERS (no ebuf dep;
//     overlaps other blocks' P1 stragglers)             -> grid.sync
//  P3 per-bucket 256-dest hist (1x, was 2x) -> dinv -> scale acc -> yb
//                                                       -> grid.sync
//  P4 aggr (proven body; h comes free from P3's hist, re-hist skipped)
// LDS phase-overlaid in 32000 B (2 blocks/CU even under 64KB accounting);
// __launch_bounds__(512,4) caps VGPR=128 so 2 blocks/CU co-reside (512>=391).
// Runtime occupancy+coop check; FALLBACK = exact R11 pipeline (173.0us).

#define NBMAX 400
#define CAP   5120   // bucket capacity: mean 4096 + 16 sigma (sigma ~ 64)

typedef short bf16x8 __attribute__((ext_vector_type(8)));
typedef float f32x4  __attribute__((ext_vector_type(4)));

__device__ inline float bflo(unsigned u) { return __uint_as_float(u << 16); }
__device__ inline float bfhi(unsigned u) { return __uint_as_float(u & 0xFFFF0000u); }
__device__ inline unsigned short f2bf(float f) {           // round-nearest-even
    unsigned u = __float_as_uint(f);
    u += 0x7FFFu + ((u >> 16) & 1u);
    return (unsigned short)(u >> 16);
}

#define MFMA __builtin_amdgcn_mfma_f32_16x16x32_bf16

// ---------------------------------------------------------------------------
// Mega kernel. smem layout (32000 B): hd[256] @0 (persists P3->P4);
// phase region ph @1024 (30976 B):
//   P0/P1 bin : sorted4 16384 | sbkt 8192 | h/hstart/hcur/gof 4x1600
//   P2  gemm  : xs[128][72] 18432 | Wb[64][72] 9216
//   P4  aggr  : ahstart 1024 | ahc 1024 | awsum 64 | sbuf[5120] 20480
// ---------------------------------------------------------------------------
__global__ __launch_bounds__(512, 4) void k_mega(
    const int* __restrict__ row, const int* __restrict__ col,
    const float* __restrict__ x, const float* __restrict__ W,
    const float* __restrict__ bias,
    int* __restrict__ gcnt, unsigned int* __restrict__ ebuf,
    unsigned short* __restrict__ yb, float* __restrict__ out,
    int E, int n, int NB)
{
    __shared__ __align__(16) char smem[32000];
    int*  hd = (int*)smem;                     // [256]
    char* ph = smem + 1024;

    cg::grid_group gg = cg::this_grid();
    int bx = blockIdx.x, t = threadIdx.x;
    int lane = t & 63, wid = t >> 6;

    // ================= P0: zero own gcnt + bin local =================
    if (t == 0 && bx < NB) gcnt[bx] = 0;

    unsigned int*   sorted4 = (unsigned int*)ph;            // 16384
    unsigned short* sbkt    = (unsigned short*)(ph + 16384);//  8192
    int* h      = (int*)(ph + 24576);
    int* hstart = (int*)(ph + 26176);
    int* hcur   = (int*)(ph + 27776);
    int* gof    = (int*)(ph + 29376);

    int base  = bx * 4096;
    int total = min(4096, E - base);           // <=0 for bx >= nbE: loops skip

    int rr[8], cc[8];
    #pragma unroll
    for (int i = 0; i < 2; ++i) {
        int e0 = (t + i * 512) * 4;
        if (e0 + 3 < total) {
            int4 r4 = *(const int4*)(row + base + e0);
            int4 c4 = *(const int4*)(col + base + e0);
            rr[i*4+0]=r4.x; rr[i*4+1]=r4.y; rr[i*4+2]=r4.z; rr[i*4+3]=r4.w;
            cc[i*4+0]=c4.x; cc[i*4+1]=c4.y; cc[i*4+2]=c4.z; cc[i*4+3]=c4.w;
        } else {
            #pragma unroll
            for (int j = 0; j < 4; ++j) {
                int e = e0 + j;
                if (e < total) { rr[i*4+j] = row[base+e]; cc[i*4+j] = col[base+e]; }
                else cc[i*4+j] = -1;
            }
        }
    }
    for (int b = t; b < NBMAX; b += 512) h[b] = 0;
    __syncthreads();
    #pragma unroll
    for (int i = 0; i < 8; ++i)
        if (cc[i] >= 0) atomicAdd(&h[cc[i] >> 8], 1);
    __syncthreads();
    if (t < 64) {                              // wave-0 scan of h
        int lo = t * 7;
        int loc[7]; int s = 0;
        #pragma unroll
        for (int i = 0; i < 7; ++i) {
            loc[i] = s;
            int idx = lo + i;
            s += (idx < NBMAX) ? h[idx] : 0;
        }
        int incl = s;
        for (int off = 1; off < 64; off <<= 1) {
            int v = __shfl_up(incl, off);
            if (t >= off) incl += v;
        }
        int ex = incl - s;
        #pragma unroll
        for (int i = 0; i < 7; ++i) {
            int idx = lo + i;
            if (idx < NBMAX) hstart[idx] = ex + loc[i];
        }
    }
    __syncthreads();
    for (int b = t; b < NBMAX; b += 512) hcur[b] = hstart[b];
    __syncthreads();
    #pragma unroll
    for (int i = 0; i < 8; ++i) {
        if (cc[i] >= 0) {
            int b = cc[i] >> 8;
            int rank = atomicAdd(&hcur[b], 1);
            sorted4[rank] = (unsigned)rr[i] | ((unsigned)(cc[i] & 255) << 24);
            sbkt[rank] = (unsigned short)b;
        }
    }
    __threadfence();
    gg.sync();                                 // ---- #1: all gcnt zeroed ----

    // ================= P1: gof atomics + copy-out =================
    for (int b = t; b < NBMAX; b += 512) {
        int m = h[b];
        gof[b] = b * CAP + (m ? atomicAdd(&gcnt[b], m) : 0);
    }
    __syncthreads();
    for (int i = t; i < total; i += 512) {
        int b = sbkt[i];
        ebuf[gof[b] + (i - hstart[b])] = sorted4[i];
    }
    __syncthreads();                           // LDS free for P2

    // ================= P2: gemm 2x128 rows into registers =================
    unsigned short (*xs)[72] = (unsigned short (*)[72])ph;           // 18432
    unsigned short (*Wb)[72] = (unsigned short (*)[72])(ph + 18432); //  9216
    long long tot64 = (long long)n * 64;

    #pragma unroll
    for (int i = 0; i < 2; ++i) {              // W: 1024 float4 chunks, once
        int idx = t + i * 512;
        int r = idx >> 4, c4 = (idx & 15) << 2;
        float4 wv = *(const float4*)(W + idx * 4);
        ushort4 wo; wo.x = f2bf(wv.x); wo.y = f2bf(wv.y); wo.z = f2bf(wv.z); wo.w = f2bf(wv.w);
        *(ushort4*)&Wb[r][c4] = wo;
    }
    int mrow = wid * 16 + (lane & 15);
    int kg   = (lane >> 4) * 8;
    int bn   = lane & 15;
    f32x4 A0 = {0.f,0.f,0.f,0.f}, A1 = A0, A2 = A0, A3 = A0;
    f32x4 B0 = A0, B1 = A0, B2 = A0, B3 = A0;

    {   // ---- sub-tile 0: rows [256bx, 256bx+128) ----
        long long xb = (long long)bx * 16384;
        #pragma unroll
        for (int i = 0; i < 4; ++i) {          // 2048 float4 chunks
            int idx = t + i * 512;
            int r = idx >> 4, c4 = (idx & 15) << 2;
            long long g = xb + (long long)idx * 4;
            float4 v;
            if (g + 3 < tot64) v = *(const float4*)(x + g);
            else {
                v.x = (g + 0 < tot64) ? x[g + 0] : 0.f;
                v.y = (g + 1 < tot64) ? x[g + 1] : 0.f;
                v.z = (g + 2 < tot64) ? x[g + 2] : 0.f;
                v.w = (g + 3 < tot64) ? x[g + 3] : 0.f;
            }
            ushort4 o; o.x = f2bf(v.x); o.y = f2bf(v.y); o.z = f2bf(v.z); o.w = f2bf(v.w);
            *(ushort4*)&xs[r][c4] = o;
        }
        __syncthreads();
        bf16x8 a0 = *(bf16x8*)&xs[mrow][kg];
        bf16x8 a1 = *(bf16x8*)&xs[mrow][32 + kg];
        { bf16x8 b0 = *(bf16x8*)&Wb[bn     ][kg], b1 = *(bf16x8*)&Wb[bn     ][32+kg];
          A0 = MFMA(a0,b0,A0,0,0,0); A0 = MFMA(a1,b1,A0,0,0,0); }
        { bf16x8 b0 = *(bf16x8*)&Wb[bn + 16][kg], b1 = *(bf16x8*)&Wb[bn + 16][32+kg];
          A1 = MFMA(a0,b0,A1,0,0,0); A1 = MFMA(a1,b1,A1,0,0,0); }
        { bf16x8 b0 = *(bf16x8*)&Wb[bn + 32][kg], b1 = *(bf16x8*)&Wb[bn + 32][32+kg];
          A2 = MFMA(a0,b0,A2,0,0,0); A2 = MFMA(a1,b1,A2,0,0,0); }
        { bf16x8 b0 = *(bf16x8*)&Wb[bn + 48][kg], b1 = *(bf16x8*)&Wb[bn + 48][32+kg];
          A3 = MFMA(a0,b0,A3,0,0,0); A3 = MFMA(a1,b1,A3,0,0,0); }
        __syncthreads();                       // xs reused by sub-tile 1
    }
    {   // ---- sub-tile 1: rows [256bx+128, 256bx+256) ----
        long long xb = (long long)bx * 16384 + 8192;
        #pragma unroll
        for (int i = 0; i < 4; ++i) {
            int idx = t + i * 512;
            int r = idx >> 4, c4 = (idx & 15) << 2;
            long long g = xb + (long long)idx * 4;
            float4 v;
            if (g + 3 < tot64) v = *(const float4*)(x + g);
            else {
                v.x = (g + 0 < tot64) ? x[g + 0] : 0.f;
                v.y = (g + 1 < tot64) ? x[g + 1] : 0.f;
                v.z = (g + 2 < tot64) ? x[g + 2] : 0.f;
                v.w = (g + 3 < tot64) ? x[g + 3] : 0.f;
            }
            ushort4 o; o.x = f2bf(v.x); o.y = f2bf(v.y); o.z = f2bf(v.z); o.w = f2bf(v.w);
            *(ushort4*)&xs[r][c4] = o;
        }
        __syncthreads();
        bf16x8 a0 = *(bf16x8*)&xs[mrow][kg];
        bf16x8 a1 = *(bf16x8*)&xs[mrow][32 + kg];
        { bf16x8 b0 = *(bf16x8*)&Wb[bn     ][kg], b1 = *(bf16x8*)&Wb[bn     ][32+kg];
          B0 = MFMA(a0,b0,B0,0,0,0); B0 = MFMA(a1,b1,B0,0,0,0); }
        { bf16x8 b0 = *(bf16x8*)&Wb[bn + 16][kg], b1 = *(bf16x8*)&Wb[bn + 16][32+kg];
          B1 = MFMA(a0,b0,B1,0,0,0); B1 = MFMA(a1,b1,B1,0,0,0); }
        { bf16x8 b0 = *(bf16x8*)&Wb[bn + 32][kg], b1 = *(bf16x8*)&Wb[bn + 32][32+kg];
          B2 = MFMA(a0,b0,B2,0,0,0); B2 = MFMA(a1,b1,B2,0,0,0); }
        { bf16x8 b0 = *(bf16x8*)&Wb[bn + 48][kg], b1 = *(bf16x8*)&Wb[bn + 48][32+kg];
          B3 = MFMA(a0,b0,B3,0,0,0); B3 = MFMA(a1,b1,B3,0,0,0); }
    }
    __threadfence();
    gg.sync();                                 // ---- #2: ebuf complete ----

    // ================= P3: 1x hist -> dinv -> scale -> yb =================
    if (t < 256) hd[t] = 0;
    __syncthreads();
    int s0  = bx * CAP;
    int cnt = (bx < NB) ? min(gcnt[bx], CAP) : 0;
    for (int i = t; i < cnt; i += 512) atomicAdd(&hd[ebuf[s0 + i] >> 24], 1);
    __syncthreads();
    {
        // C/D layout: col = lane&15, row = (lane>>4)*4 + reg  [m89-verified]
        int lr0 = wid * 16 + (lane >> 4) * 4;
        #pragma unroll
        for (int i = 0; i < 4; ++i) {
            int lr = lr0 + i;
            int r  = bx * 256 + lr;
            if (r < n) {
                float dv = rsqrtf((float)hd[lr] + 1.0f);
                long long ro = (long long)r * 64 + bn;
                yb[ro +  0] = f2bf(dv * A0[i]);
                yb[ro + 16] = f2bf(dv * A1[i]);
                yb[ro + 32] = f2bf(dv * A2[i]);
                yb[ro + 48] = f2bf(dv * A3[i]);
            }
            int r2 = r + 128, lr2 = lr + 128;
            if (r2 < n) {
                float dv = rsqrtf((float)hd[lr2] + 1.0f);
                long long ro = (long long)r2 * 64 + bn;
                yb[ro +  0] = f2bf(dv * B0[i]);
                yb[ro + 16] = f2bf(dv * B1[i]);
                yb[ro + 32] = f2bf(dv * B2[i]);
                yb[ro + 48] = f2bf(dv * B3[i]);
            }
        }
    }
    __threadfence();
    gg.sync();                                 // ---- #3: yb complete ----

    // ================= P4: aggr (h = hd from P3, no re-hist) ==============
    int* ahstart = (int*)ph;                   // 1024
    int* ahc     = (int*)(ph + 1024);          // 1024
    int* awsum   = (int*)(ph + 2048);          // 64
    int* sbuf    = (int*)(ph + 2112);          // 20480
    if (t < 256) {                             // wave-shfl inclusive scan of hd
        int v = hd[t];
        int l = t & 63, w4 = t >> 6;
        int incl = v;
        #pragma unroll
        for (int off = 1; off < 64; off <<= 1) {
            int u = __shfl_up(incl, off);
            if (l >= off) incl += u;
        }
        ahstart[t] = incl;
        if (l == 63) awsum[w4] = incl;
    }
    __syncthreads();
    if (t < 256) {
        int w4 = t >> 6;
        int add = 0;
        for (int w = 0; w < w4; ++w) add += awsum[w];
        int ex = ahstart[t] - hd[t] + add;     // exclusive prefix
        ahstart[t] = ex;
        ahc[t] = ex;
    }
    __syncthreads();
    for (int i = t; i < cnt; i += 512) {       // counting-sort scatter (re-read)
        unsigned p = ebuf[s0 + i];
        int rk = atomicAdd(&ahc[p >> 24], 1);
        sbuf[rk] = (int)(p & 0x1FFFFu);
    }
    __syncthreads();

    int g = lane >> 4, q = lane & 15;          // 8 waves x 4 groups = 32/round
    #pragma unroll 1
    for (int r = 0; r < 8; ++r) {
        int cl = r * 32 + wid * 4 + g;
        int c = bx * 256 + cl;
        if (c >= n) continue;                  // no barriers below: safe
        int start = ahstart[cl], len = hd[cl];
        float a0 = 0.f, a1 = 0.f, a2 = 0.f, a3 = 0.f;
        if (len > 0) {
            int sc = sbuf[start];              // prefetched src
            for (int i = 0; i < len; ++i) {
                int sn = (i + 1 < len) ? sbuf[start + i + 1] : 0;
                float2 v = *(const float2*)(yb + (long long)sc * 64 + (q << 2));
                unsigned u0 = __float_as_uint(v.x), u1 = __float_as_uint(v.y);
                a0 += bflo(u0); a1 += bfhi(u0);
                a2 += bflo(u1); a3 += bfhi(u1);
                sc = sn;
            }
        }
        {   // self loop
            float2 v = *(const float2*)(yb + (long long)c * 64 + (q << 2));
            unsigned u0 = __float_as_uint(v.x), u1 = __float_as_uint(v.y);
            a0 += bflo(u0); a1 += bfhi(u0);
            a2 += bflo(u1); a3 += bfhi(u1);
        }
        float dc = rsqrtf((float)len + 1.0f);
        float4 bv = *(const float4*)(bias + (q << 2));
        *(float4*)(out + (long long)c * 64 + (q << 2)) =
            make_float4(dc * a0 + bv.x, dc * a1 + bv.y,
                        dc * a2 + bv.z, dc * a3 + bv.w);
    }
}

// ======================= FALLBACK: exact R11 pipeline =======================
__global__ __launch_bounds__(512) void k_bin(const int* __restrict__ row,
                                             const int* __restrict__ col,
                                             int* __restrict__ gcnt,
                                             unsigned int* __restrict__ ebuf, int E) {
    __shared__ unsigned int   sorted4[4096];
    __shared__ unsigned short sbkt[4096];
    __shared__ int h[NBMAX], hstart[NBMAX], hcur[NBMAX], gof[NBMAX];
    int t = threadIdx.x;
    int base = blockIdx.x * 4096;
    int total = min(4096, E - base);

    int rr[8], cc[8];
    #pragma unroll
    for (int i = 0; i < 2; ++i) {
        int e0 = (t + i * 512) * 4;
        if (e0 + 3 < total) {
            int4 r4 = *(const int4*)(row + base + e0);
            int4 c4 = *(const int4*)(col + base + e0);
            rr[i*4+0]=r4.x; rr[i*4+1]=r4.y; rr[i*4+2]=r4.z; rr[i*4+3]=r4.w;
            cc[i*4+0]=c4.x; cc[i*4+1]=c4.y; cc[i*4+2]=c4.z; cc[i*4+3]=c4.w;
        } else {
            #pragma unroll
            for (int j = 0; j < 4; ++j) {
                int e = e0 + j;
                if (e < total) { rr[i*4+j] = row[base+e]; cc[i*4+j] = col[base+e]; }
                else cc[i*4+j] = -1;
            }
        }
    }
    for (int b = t; b < NBMAX; b += 512) h[b] = 0;
    __syncthreads();
    #pragma unroll
    for (int i = 0; i < 8; ++i)
        if (cc[i] >= 0) atomicAdd(&h[cc[i] >> 8], 1);
    __syncthreads();
    if (t < 64) {
        int lo = t * 7;
        int loc[7]; int s = 0;
        #pragma unroll
        for (int i = 0; i < 7; ++i) {
            loc[i] = s;
            int idx = lo + i;
            s += (idx < NBMAX) ? h[idx] : 0;
        }
        int incl = s;
        for (int off = 1; off < 64; off <<= 1) {
            int v = __shfl_up(incl, off);
            if (t >= off) incl += v;
        }
        int ex = incl - s;
        #pragma unroll
        for (int i = 0; i < 7; ++i) {
            int idx = lo + i;
            if (idx < NBMAX) hstart[idx] = ex + loc[i];
        }
    }
    __syncthreads();
    for (int b = t; b < NBMAX; b += 512) hcur[b] = hstart[b];
    __syncthreads();
    #pragma unroll
    for (int i = 0; i < 8; ++i) {
        if (cc[i] >= 0) {
            int b = cc[i] >> 8;
            int rank = atomicAdd(&hcur[b], 1);
            sorted4[rank] = (unsigned)rr[i] | ((unsigned)(cc[i] & 255) << 24);
            sbkt[rank] = (unsigned short)b;
        }
    }
    for (int b = t; b < NBMAX; b += 512) {
        int m = h[b];
        gof[b] = b * CAP + (m ? atomicAdd(&gcnt[b], m) : 0);
    }
    __syncthreads();
    for (int i = t; i < total; i += 512) {
        int b = sbkt[i];
        ebuf[gof[b] + (i - hstart[b])] = sorted4[i];
    }
}

__global__ __launch_bounds__(512) void k_gemmcnt(const float* __restrict__ x,
                                                 const float* __restrict__ W,
                                                 const unsigned int* __restrict__ ebuf,
                                                 const int* __restrict__ gcnt,
                                                 unsigned short* __restrict__ yb, int n) {
    __shared__ __align__(16) unsigned short xs[128][72];
    __shared__ __align__(16) unsigned short Wb[64][72];
    __shared__ int hd[128];
    int t = threadIdx.x;
    long long total = (long long)n * 64;
    long long xbase = (long long)blockIdx.x * 8192;
    if (t < 128) hd[t] = 0;
    #pragma unroll
    for (int i = 0; i < 4; ++i) {
        int idx = t + i * 512;
        int r = idx >> 4, c4 = (idx & 15) << 2;
        long long g = xbase + (long long)idx * 4;
        float4 v;
        if (g + 3 < total) v = *(const float4*)(x + g);
        else {
            v.x = (g + 0 < total) ? x[g + 0] : 0.f;
            v.y = (g + 1 < total) ? x[g + 1] : 0.f;
            v.z = (g + 2 < total) ? x[g + 2] : 0.f;
            v.w = (g + 3 < total) ? x[g + 3] : 0.f;
        }
        ushort4 o; o.x = f2bf(v.x); o.y = f2bf(v.y); o.z = f2bf(v.z); o.w = f2bf(v.w);
        *(ushort4*)&xs[r][c4] = o;
    }
    #pragma unroll
    for (int i = 0; i < 2; ++i) {
        int idx = t + i * 512;
        int r = idx >> 4, c4 = (idx & 15) << 2;
        float4 wv = *(const float4*)(W + idx * 4);
        ushort4 wo; wo.x = f2bf(wv.x); wo.y = f2bf(wv.y); wo.z = f2bf(wv.z); wo.w = f2bf(wv.w);
        *(ushort4*)&Wb[r][c4] = wo;
    }
    {
        int bb  = blockIdx.x >> 1;
        int sub = blockIdx.x & 1;
        int s0 = bb * CAP;
        int count = min(gcnt[bb], CAP);
        for (int i = t; i < count; i += 512) {
            unsigned d = ebuf[s0 + i] >> 24;
            if ((int)(d >> 7) == sub) atomicAdd(&hd[d & 127], 1);
        }
    }
    __syncthreads();
    int lane = t & 63, wid = t >> 6;
    int m  = wid * 16 + (lane & 15);
    int kg = (lane >> 4) * 8;
    bf16x8 a0 = *(bf16x8*)&xs[m][kg];
    bf16x8 a1 = *(bf16x8*)&xs[m][32 + kg];
    int bn = lane & 15;
    f32x4 acc0 = {0.f,0.f,0.f,0.f}, acc1 = acc0, acc2 = acc0, acc3 = acc0;
    {
        bf16x8 b0 = *(bf16x8*)&Wb[bn][kg], b1 = *(bf16x8*)&Wb[bn][32 + kg];
        acc0 = MFMA(a0, b0, acc0, 0, 0, 0);
        acc0 = MFMA(a1, b1, acc0, 0, 0, 0);
    }
    {
        bf16x8 b0 = *(bf16x8*)&Wb[bn + 16][kg], b1 = *(bf16x8*)&Wb[bn + 16][32 + kg];
        acc1 = MFMA(a0, b0, acc1, 0, 0, 0);
        acc1 = MFMA(a1, b1, acc1, 0, 0, 0);
    }
    {
        bf16x8 b0 = *(bf16x8*)&Wb[bn + 32][kg], b1 = *(bf16x8*)&Wb[bn + 32][32 + kg];
        acc2 = MFMA(a0, b0, acc2, 0, 0, 0);
        acc2 = MFMA(a1, b1, acc2, 0, 0, 0);
    }
    {
        bf16x8 b0 = *(bf16x8*)&Wb[bn + 48][kg], b1 = *(bf16x8*)&Wb[bn + 48][32 + kg];
        acc3 = MFMA(a0, b0, acc3, 0, 0, 0);
        acc3 = MFMA(a1, b1, acc3, 0, 0, 0);
    }
    int lr0 = wid * 16 + (lane >> 4) * 4;
    int rbase = blockIdx.x * 128 + lr0;
    #pragma unroll
    for (int i = 0; i < 4; ++i) {
        int r = rbase + i;
        if (r < n) {
            float dv = rsqrtf((float)hd[lr0 + i] + 1.0f);
            long long ro = (long long)r * 64 + bn;
            yb[ro +  0] = f2bf(dv * acc0[i]);
            yb[ro + 16] = f2bf(dv * acc1[i]);
            yb[ro + 32] = f2bf(dv * acc2[i]);
            yb[ro + 48] = f2bf(dv * acc3[i]);
        }
    }
}

__global__ __launch_bounds__(1024) void k_aggr(const unsigned int* __restrict__ ebuf,
                                               const int* __restrict__ gcnt,
                                               const unsigned short* __restrict__ yb,
                                               const float* __restrict__ bias,
                                               float* __restrict__ out, int n) {
    __shared__ int h[256], hstart[256], hc[256], wsum[4];
    __shared__ int sbuf[CAP];
    int b = blockIdx.x, t = threadIdx.x;
    int s0 = b * CAP;
    int count = min(gcnt[b], CAP);

    if (t < 256) h[t] = 0;
    __syncthreads();
    unsigned rec[5];
    #pragma unroll
    for (int k = 0; k < 5; ++k) {
        int i = t + k * 1024;
        if (i < count) {
            unsigned p = ebuf[s0 + i];
            rec[k] = p;
            atomicAdd(&h[p >> 24], 1);
        }
    }
    __syncthreads();
    if (t < 256) {
        int v = h[t];
        int lane = t & 63, wid = t >> 6;
        int incl = v;
        #pragma unroll
        for (int off = 1; off < 64; off <<= 1) {
            int u = __shfl_up(incl, off);
            if (lane >= off) incl += u;
        }
        hstart[t] = incl;
        if (lane == 63) wsum[wid] = incl;
    }
    __syncthreads();
    if (t < 256) {
        int wid = t >> 6;
        int add = 0;
        for (int w = 0; w < wid; ++w) add += wsum[w];
        int ex = hstart[t] - h[t] + add;
        hstart[t] = ex;
        hc[t] = ex;
    }
    __syncthreads();
    #pragma unroll
    for (int k = 0; k < 5; ++k) {
        int i = t + k * 1024;
        if (i < count) {
            unsigned p = rec[k];
            int r = atomicAdd(&hc[p >> 24], 1);
            sbuf[r] = (int)(p & 0x1FFFFu);
        }
    }
    __syncthreads();

    int lane = t & 63, w = t >> 6;
    int g = lane >> 4, q = lane & 15;
    #pragma unroll
    for (int r = 0; r < 4; ++r) {
        int cl = r * 64 + w * 4 + g;
        int c = b * 256 + cl;
        if (c >= n) continue;
        int start = hstart[cl], len = h[cl];
        float a0 = 0.f, a1 = 0.f, a2 = 0.f, a3 = 0.f;
        if (len > 0) {
            int sc = sbuf[start];
            for (int i = 0; i < len; ++i) {
                int sn = (i + 1 < len) ? sbuf[start + i + 1] : 0;
                float2 v = *(const float2*)(yb + (long long)sc * 64 + (q << 2));
                unsigned u0 = __float_as_uint(v.x), u1 = __float_as_uint(v.y);
                a0 += bflo(u0); a1 += bfhi(u0);
                a2 += bflo(u1); a3 += bfhi(u1);
                sc = sn;
            }
        }
        {
            float2 v = *(const float2*)(yb + (long long)c * 64 + (q << 2));
            unsigned u0 = __float_as_uint(v.x), u1 = __float_as_uint(v.y);
            a0 += bflo(u0); a1 += bfhi(u0);
            a2 += bflo(u1); a3 += bfhi(u1);
        }
        float dc = rsqrtf((float)len + 1.0f);
        float4 bv = *(const float4*)(bias + (q << 2));
        *(float4*)(out + (long long)c * 64 + (q << 2)) =
            make_float4(dc * a0 + bv.x, dc * a1 + bv.y,
                        dc * a2 + bv.z, dc * a3 + bv.w);
    }
}

extern "C" void kernel_launch(void* const* d_in, const int* in_sizes, int n_in,
                              void* d_out, int out_size, void* d_ws, size_t ws_size,
                              hipStream_t stream) {
    const float* x    = (const float*)d_in[0];
    const int*   ei   = (const int*)d_in[1];
    // d_in[2] = x0 (unused: use_init=False)
    const float* W    = (const float*)d_in[3];
    const float* bias = (const float*)d_in[4];
    float* out = (float*)d_out;

    int n = in_sizes[0] / 64;
    int E = in_sizes[1] / 2;
    const int* row = ei;        // source
    const int* col = ei + E;    // target

    int NB = (n + 255) / 256;   // 391 (<= NBMAX, <= 512)

    char* ws = (char*)d_ws;
    size_t off = 0;
    auto alloc = [&](size_t bytes) { char* p = ws + off; off += (bytes + 15) & ~size_t(15); return p; };
    int*            gcnt = (int*)  alloc((size_t)NB * 4);
    unsigned short* yb   = (unsigned short*)alloc((size_t)n * 64 * 2);
    unsigned int*   ebuf = (unsigned int*)alloc((size_t)NB * CAP * 4);

    int nbE  = (E + 4095) / 4096;              // 391
    int grid = (nbE > NB) ? nbE : NB;

    bool coop = false;
    int dev = 0;
    if (hipGetDevice(&dev) == hipSuccess) {
        int attr = 0, ncu = 0, maxblk = 0;
        hipDeviceGetAttribute(&attr, hipDeviceAttributeCooperativeLaunch, dev);
        hipDeviceGetAttribute(&ncu, hipDeviceAttributeMultiprocessorCount, dev);
        hipError_t e = hipOccupancyMaxActiveBlocksPerMultiprocessor(&maxblk, k_mega, 512, 0);
        if (attr && ncu > 0 && e == hipSuccess && (long long)maxblk * ncu >= grid) coop = true;
    }

    if (coop) {
        void* args[] = {(void*)&row, (void*)&col, (void*)&x, (void*)&W, (void*)&bias,
                        (void*)&gcnt, (void*)&ebuf, (void*)&yb, (void*)&out,
                        (void*)&E, (void*)&n, (void*)&NB};
        hipLaunchCooperativeKernel((void*)k_mega, dim3(grid), dim3(512), args, 0, stream);
    } else {
        hipMemsetAsync(gcnt, 0, (size_t)NB * 4, stream);
        k_bin    <<<nbE, 512, 0, stream>>>(row, col, gcnt, ebuf, E);
        k_gemmcnt<<<(n + 127) / 128, 512, 0, stream>>>(x, W, ebuf, gcnt, yb, n);
        k_aggr   <<<NB, 1024, 0, stream>>>(ebuf, gcnt, yb, bias, out, n);
    }
}

// Round 13
// 174.006 us; speedup vs baseline: 2.9046x; 2.9046x over previous
//
#include <hip/hip_runtime.h>

// GCN layer: out = Ahat @ x @ W^T + bias, Ahat = D^-1/2 (A + I) D^-1/2
// Pipeline (4 dispatches): memset(gcnt) -> k_bin (512t): bucket binning by
// dst>>8, LDS counting sort, contiguous run writes -> k_gemmcnt (512t/128
// rows): per-bucket 128-dest LDS histogram (fused with tile staging, 2
// blocks/bucket) + y' = rsqrt(deg+1)*(x@W^T) via bf16 MFMA -> k_aggr
// (proven body): LDS counting-sort by dst&255 + per-dest gather, dest scale
// rsqrtf(len+1).
// R13: exact revert to R11 (173.0us best). R12's cooperative mega-kernel was
// 400us (grid.sync across 8 XCDs >> dispatch-boundary cost). Toxic list now
// complete: global-atomic hot paths (R6), device-scope spins (R10),
// grid-wide sync (R12). 4 dispatches is the floor given data deps.

#define NBMAX 400
#define CAP   5120   // bucket capacity: mean 4096 + 16 sigma (sigma ~ 64)

typedef short bf16x8 __attribute__((ext_vector_type(8)));
typedef float f32x4  __attribute__((ext_vector_type(4)));

__device__ inline float bflo(unsigned u) { return __uint_as_float(u << 16); }
__device__ inline float bfhi(unsigned u) { return __uint_as_float(u & 0xFFFF0000u); }
__device__ inline unsigned short f2bf(float f) {           // round-nearest-even
    unsigned u = __float_as_uint(f);
    u += 0x7FFFu + ((u >> 16) & 1u);
    return (unsigned short)(u >> 16);
}

// Chunk-local LDS counting sort by bucket (dst>>8); contiguous run copy-out of
// packed (src | (dst&255)<<24) records into fixed-stride bucket regions.
// 512 threads: 8 edges/thread; 8 waves overlap each latency phase (R7).
// gcnt[b] zeroed by memset; region base = b*CAP.
__global__ __launch_bounds__(512) void k_bin(const int* __restrict__ row,
                                             const int* __restrict__ col,
                                             int* __restrict__ gcnt,
                                             unsigned int* __restrict__ ebuf, int E) {
    __shared__ unsigned int   sorted4[4096];   // 16 KB packed records
    __shared__ unsigned short sbkt[4096];      //  8 KB bucket id per slot
    __shared__ int h[NBMAX], hstart[NBMAX], hcur[NBMAX], gof[NBMAX];
    int t = threadIdx.x;
    int base = blockIdx.x * 4096;
    int total = min(4096, E - base);

    int rr[8], cc[8];
    #pragma unroll
    for (int i = 0; i < 2; ++i) {
        int e0 = (t + i * 512) * 4;
        if (e0 + 3 < total) {
            int4 r4 = *(const int4*)(row + base + e0);
            int4 c4 = *(const int4*)(col + base + e0);
            rr[i*4+0]=r4.x; rr[i*4+1]=r4.y; rr[i*4+2]=r4.z; rr[i*4+3]=r4.w;
            cc[i*4+0]=c4.x; cc[i*4+1]=c4.y; cc[i*4+2]=c4.z; cc[i*4+3]=c4.w;
        } else {
            #pragma unroll
            for (int j = 0; j < 4; ++j) {
                int e = e0 + j;
                if (e < total) { rr[i*4+j] = row[base+e]; cc[i*4+j] = col[base+e]; }
                else cc[i*4+j] = -1;
            }
        }
    }
    for (int b = t; b < NBMAX; b += 512) h[b] = 0;
    __syncthreads();
    #pragma unroll
    for (int i = 0; i < 8; ++i)
        if (cc[i] >= 0) atomicAdd(&h[cc[i] >> 8], 1);
    __syncthreads();
    if (t < 64) {                              // wave-0 scan of h
        int lo = t * 7;
        int loc[7]; int s = 0;
        #pragma unroll
        for (int i = 0; i < 7; ++i) {
            loc[i] = s;
            int idx = lo + i;
            s += (idx < NBMAX) ? h[idx] : 0;
        }
        int incl = s;
        for (int off = 1; off < 64; off <<= 1) {
            int v = __shfl_up(incl, off);
            if (t >= off) incl += v;
        }
        int ex = incl - s;
        #pragma unroll
        for (int i = 0; i < 7; ++i) {
            int idx = lo + i;
            if (idx < NBMAX) hstart[idx] = ex + loc[i];
        }
    }
    __syncthreads();
    for (int b = t; b < NBMAX; b += 512) hcur[b] = hstart[b];
    __syncthreads();
    #pragma unroll
    for (int i = 0; i < 8; ++i) {
        if (cc[i] >= 0) {
            int b = cc[i] >> 8;
            int rank = atomicAdd(&hcur[b], 1);
            sorted4[rank] = (unsigned)rr[i] | ((unsigned)(cc[i] & 255) << 24);
            sbkt[rank] = (unsigned short)b;
        }
    }
    for (int b = t; b < NBMAX; b += 512) {
        int m = h[b];
        gof[b] = b * CAP + (m ? atomicAdd(&gcnt[b], m) : 0);
    }
    __syncthreads();
    for (int i = t; i < total; i += 512) {     // contiguous per-bucket runs
        int b = sbkt[i];
        ebuf[gof[b] + (i - hstart[b])] = sorted4[i];
    }
}

// y' = rsqrt(deg+1) * (x @ W^T) via bf16 MFMA 16x16x32; 128 rows per block,
// 512 threads / 8 waves. Degree histogram for this block's 128 rows computed
// in-kernel from the bucket's ebuf run (2 blocks per bucket, coalesced,
// L2/L3-hot, overlaps the tile staging loads). LDS rows padded to 72 bf16.
__global__ __launch_bounds__(512) void k_gemmcnt(const float* __restrict__ x,
                                                 const float* __restrict__ W,
                                                 const unsigned int* __restrict__ ebuf,
                                                 const int* __restrict__ gcnt,
                                                 unsigned short* __restrict__ yb, int n) {
    __shared__ __align__(16) unsigned short xs[128][72];
    __shared__ __align__(16) unsigned short Wb[64][72];
    __shared__ int hd[128];
    int t = threadIdx.x;
    long long total = (long long)n * 64;
    long long xbase = (long long)blockIdx.x * 8192;
    if (t < 128) hd[t] = 0;
    #pragma unroll
    for (int i = 0; i < 4; ++i) {              // x: 2048 float4 chunks
        int idx = t + i * 512;                 // 0..2047
        int r = idx >> 4, c4 = (idx & 15) << 2;
        long long g = xbase + (long long)idx * 4;
        float4 v;
        if (g + 3 < total) v = *(const float4*)(x + g);
        else {
            v.x = (g + 0 < total) ? x[g + 0] : 0.f;
            v.y = (g + 1 < total) ? x[g + 1] : 0.f;
            v.z = (g + 2 < total) ? x[g + 2] : 0.f;
            v.w = (g + 3 < total) ? x[g + 3] : 0.f;
        }
        ushort4 o; o.x = f2bf(v.x); o.y = f2bf(v.y); o.z = f2bf(v.z); o.w = f2bf(v.w);
        *(ushort4*)&xs[r][c4] = o;
    }
    #pragma unroll
    for (int i = 0; i < 2; ++i) {              // W: 1024 float4 chunks
        int idx = t + i * 512;                 // 0..1023
        int r = idx >> 4, c4 = (idx & 15) << 2;
        float4 wv = *(const float4*)(W + idx * 4);     // W: 4096 floats
        ushort4 wo; wo.x = f2bf(wv.x); wo.y = f2bf(wv.y); wo.z = f2bf(wv.z); wo.w = f2bf(wv.w);
        *(ushort4*)&Wb[r][c4] = wo;
    }
    {   // degree hist for this block's 128 dests (half of the bucket)
        int bb  = blockIdx.x >> 1;             // bucket
        int sub = blockIdx.x & 1;              // which 128-dest half
        int s0 = bb * CAP;
        int count = min(gcnt[bb], CAP);
        for (int i = t; i < count; i += 512) {
            unsigned d = ebuf[s0 + i] >> 24;
            if ((int)(d >> 7) == sub) atomicAdd(&hd[d & 127], 1);
        }
    }
    __syncthreads();
    int lane = t & 63, wid = t >> 6;           // 8 waves: rows wid*16..+16
    int m  = wid * 16 + (lane & 15);
    int kg = (lane >> 4) * 8;
    bf16x8 a0 = *(bf16x8*)&xs[m][kg];
    bf16x8 a1 = *(bf16x8*)&xs[m][32 + kg];
    int bn = lane & 15;
    f32x4 acc0 = {0.f,0.f,0.f,0.f}, acc1 = acc0, acc2 = acc0, acc3 = acc0;
    {
        bf16x8 b0 = *(bf16x8*)&Wb[bn][kg], b1 = *(bf16x8*)&Wb[bn][32 + kg];
        acc0 = __builtin_amdgcn_mfma_f32_16x16x32_bf16(a0, b0, acc0, 0, 0, 0);
        acc0 = __builtin_amdgcn_mfma_f32_16x16x32_bf16(a1, b1, acc0, 0, 0, 0);
    }
    {
        bf16x8 b0 = *(bf16x8*)&Wb[bn + 16][kg], b1 = *(bf16x8*)&Wb[bn + 16][32 + kg];
        acc1 = __builtin_amdgcn_mfma_f32_16x16x32_bf16(a0, b0, acc1, 0, 0, 0);
        acc1 = __builtin_amdgcn_mfma_f32_16x16x32_bf16(a1, b1, acc1, 0, 0, 0);
    }
    {
        bf16x8 b0 = *(bf16x8*)&Wb[bn + 32][kg], b1 = *(bf16x8*)&Wb[bn + 32][32 + kg];
        acc2 = __builtin_amdgcn_mfma_f32_16x16x32_bf16(a0, b0, acc2, 0, 0, 0);
        acc2 = __builtin_amdgcn_mfma_f32_16x16x32_bf16(a1, b1, acc2, 0, 0, 0);
    }
    {
        bf16x8 b0 = *(bf16x8*)&Wb[bn + 48][kg], b1 = *(bf16x8*)&Wb[bn + 48][32 + kg];
        acc3 = __builtin_amdgcn_mfma_f32_16x16x32_bf16(a0, b0, acc3, 0, 0, 0);
        acc3 = __builtin_amdgcn_mfma_f32_16x16x32_bf16(a1, b1, acc3, 0, 0, 0);
    }
    // C/D layout: col = lane&15, row = (lane>>4)*4 + reg  [m89-verified]
    int lr0 = wid * 16 + (lane >> 4) * 4;
    int rbase = blockIdx.x * 128 + lr0;
    #pragma unroll
    for (int i = 0; i < 4; ++i) {
        int r = rbase + i;
        if (r < n) {
            float dv = rsqrtf((float)hd[lr0 + i] + 1.0f);
            long long ro = (long long)r * 64 + bn;
            yb[ro +  0] = f2bf(dv * acc0[i]);
            yb[ro + 16] = f2bf(dv * acc1[i]);
            yb[ro + 32] = f2bf(dv * acc2[i]);
            yb[ro + 48] = f2bf(dv * acc3[i]);
        }
    }
}

// FUSED sort+gather: one 1024-thread block per bucket. LDS counting sort by
// dst&255 (sbuf never leaves LDS); then each 16-lane group gathers one dest's
// src list (broadcast ds_read) and writes out directly. Dest scale computed
// locally: dc = rsqrtf(len+1).
__global__ __launch_bounds__(1024) void k_aggr(const unsigned int* __restrict__ ebuf,
                                               const int* __restrict__ gcnt,
                                               const unsigned short* __restrict__ yb,
                                               const float* __restrict__ bias,
                                               float* __restrict__ out, int n) {
    __shared__ int h[256], hstart[256], hc[256], wsum[4];
    __shared__ int sbuf[CAP];                  // 20 KB, LDS-only
    int b = blockIdx.x, t = threadIdx.x;
    int s0 = b * CAP;
    int count = min(gcnt[b], CAP);

    if (t < 256) h[t] = 0;
    __syncthreads();
    unsigned rec[5];
    #pragma unroll
    for (int k = 0; k < 5; ++k) {              // coalesced load + LDS hist
        int i = t + k * 1024;
        if (i < count) {
            unsigned p = ebuf[s0 + i];
            rec[k] = p;
            atomicAdd(&h[p >> 24], 1);
        }
    }
    __syncthreads();
    if (t < 256) {                             // wave-shfl inclusive scan
        int v = h[t];
        int lane = t & 63, wid = t >> 6;
        int incl = v;
        #pragma unroll
        for (int off = 1; off < 64; off <<= 1) {
            int u = __shfl_up(incl, off);
            if (lane >= off) incl += u;
        }
        hstart[t] = incl;                      // temp: inclusive
        if (lane == 63) wsum[wid] = incl;
    }
    __syncthreads();
    if (t < 256) {
        int wid = t >> 6;
        int add = 0;
        for (int w = 0; w < wid; ++w) add += wsum[w];
        int ex = hstart[t] - h[t] + add;       // exclusive prefix
        hstart[t] = ex;
        hc[t] = ex;
    }
    __syncthreads();
    #pragma unroll
    for (int k = 0; k < 5; ++k) {              // counting-sort scatter (LDS)
        int i = t + k * 1024;
        if (i < count) {
            unsigned p = rec[k];
            int r = atomicAdd(&hc[p >> 24], 1);
            sbuf[r] = (int)(p & 0x1FFFFu);
        }
    }
    __syncthreads();

    // Gather: 16 waves x 4 groups = 64 dest-slots; 4 rounds cover 256 dests.
    int lane = t & 63, w = t >> 6;
    int g = lane >> 4, q = lane & 15;
    #pragma unroll
    for (int r = 0; r < 4; ++r) {
        int cl = r * 64 + w * 4 + g;
        int c = b * 256 + cl;
        if (c >= n) continue;                  // no barriers below: safe
        int start = hstart[cl], len = h[cl];
        float a0 = 0.f, a1 = 0.f, a2 = 0.f, a3 = 0.f;
        if (len > 0) {
            int sc = sbuf[start];              // prefetched src
            for (int i = 0; i < len; ++i) {
                int sn = (i + 1 < len) ? sbuf[start + i + 1] : 0;
                float2 v = *(const float2*)(yb + (long long)sc * 64 + (q << 2));
                unsigned u0 = __float_as_uint(v.x), u1 = __float_as_uint(v.y);
                a0 += bflo(u0); a1 += bfhi(u0);
                a2 += bflo(u1); a3 += bfhi(u1);
                sc = sn;
            }
        }
        {   // self loop
            float2 v = *(const float2*)(yb + (long long)c * 64 + (q << 2));
            unsigned u0 = __float_as_uint(v.x), u1 = __float_as_uint(v.y);
            a0 += bflo(u0); a1 += bfhi(u0);
            a2 += bflo(u1); a3 += bfhi(u1);
        }
        float dc = rsqrtf((float)len + 1.0f);
        float4 bv = *(const float4*)(bias + (q << 2));
        *(float4*)(out + (long long)c * 64 + (q << 2)) =
            make_float4(dc * a0 + bv.x, dc * a1 + bv.y,
                        dc * a2 + bv.z, dc * a3 + bv.w);
    }
}

extern "C" void kernel_launch(void* const* d_in, const int* in_sizes, int n_in,
                              void* d_out, int out_size, void* d_ws, size_t ws_size,
                              hipStream_t stream) {
    const float* x    = (const float*)d_in[0];
    const int*   ei   = (const int*)d_in[1];
    // d_in[2] = x0 (unused: use_init=False)
    const float* W    = (const float*)d_in[3];
    const float* bias = (const float*)d_in[4];
    float* out = (float*)d_out;

    int n = in_sizes[0] / 64;
    int E = in_sizes[1] / 2;
    const int* row = ei;        // source
    const int* col = ei + E;    // target

    int NB = (n + 255) / 256;   // 391 (<= NBMAX, <= 512)

    char* ws = (char*)d_ws;
    size_t off = 0;
    auto alloc = [&](size_t bytes) { char* p = ws + off; off += (bytes + 15) & ~size_t(15); return p; };
    int*            gcnt = (int*)  alloc((size_t)NB * 4);
    unsigned short* yb   = (unsigned short*)alloc((size_t)n * 64 * 2);
    unsigned int*   ebuf = (unsigned int*)alloc((size_t)NB * CAP * 4);

    int nbE = (E + 4095) / 4096;

    hipMemsetAsync(gcnt, 0, (size_t)NB * 4, stream);
    k_bin    <<<nbE, 512, 0, stream>>>(row, col, gcnt, ebuf, E);
    k_gemmcnt<<<(n + 127) / 128, 512, 0, stream>>>(x, W, ebuf, gcnt, yb, n);
    k_aggr   <<<NB, 1024, 0, stream>>>(ebuf, gcnt, yb, bias, out, n);
}